// Round 2
// baseline (256.715 us; speedup 1.0000x reference)
//
#include <hip/hip_runtime.h>
#include <math.h>

#define NB 8
#define NGRID 343
#define HID 64
#define NPATH 20

// ---------------- compile-time Clifford tables (Cl(3,0), blade order:
// 1, e1, e2, e3, e12, e13, e23, e123 — matches reference combinations order) ---
struct Tab {
  int prod_idx[8][8];  // blade index of product blade_k * blade_m
  int prod_sgn[8][8];  // sign of that product
  int pid[4][4][4];    // path id for (grade_left, grade_out, grade_right), 20 = dead
  int grade[8];        // grade of blade idx
  int kk_idx[8][8];    // for (l,m): unique k with prod(k,m) = +-l
  int kk_sgn[8][8];    // C[kk, l, m]
};

constexpr Tab make_tab() {
  Tab t{};
  int mask[8]  = {0,1,2,4,3,5,6,7};  // blade idx -> bitmask
  int idxof[8] = {0,1,2,4,3,5,6,7};  // bitmask -> blade idx
  for (int k = 0; k < 8; ++k) {
    int g = 0;
    for (int b = 0; b < 3; ++b) g += (mask[k] >> b) & 1;
    t.grade[k] = g;
  }
  for (int k = 0; k < 8; ++k)
    for (int m = 0; m < 8; ++m) {
      int A = mask[k], B = mask[m];
      t.prod_idx[k][m] = idxof[A ^ B];
      int c = 0;
      for (int i = 0; i < 3; ++i)
        if ((B >> i) & 1)
          for (int j = i + 1; j < 3; ++j)
            if ((A >> j) & 1) c++;
      t.prod_sgn[k][m] = (c & 1) ? -1 : 1;
    }
  int pc = 0;
  for (int a = 0; a < 4; ++a)
    for (int b = 0; b < 4; ++b)
      for (int c = 0; c < 4; ++c) {
        bool ok = false;
        for (int k = 0; k < 8; ++k)
          for (int m = 0; m < 8; ++m)
            if (t.grade[k] == a && t.grade[m] == c &&
                t.grade[t.prod_idx[k][m]] == b)
              ok = true;
        t.pid[a][b][c] = ok ? pc++ : NPATH;
      }
  for (int l = 0; l < 8; ++l)
    for (int m = 0; m < 8; ++m)
      for (int k = 0; k < 8; ++k)
        if (t.prod_idx[k][m] == l) {
          t.kk_idx[l][m] = k;
          t.kk_sgn[l][m] = t.prod_sgn[k][m];
        }
  return t;
}
constexpr Tab TB = make_tab();

// ---------------- workspace layout (floats) ----------------
// lin0_t [4][64][36]   @ 0      (9216)  padded rows for aligned float4
// k_ws   [1024][343][8] @ 9216  (2809856)
// lins_W / gps_w / out_W are read DIRECTLY (natural layouts already have the
// reduction axis innermost -> per-thread-contiguous float4 loads).
#define OFF_LIN0T 0
#define OFF_KWS   9216

// ---------------- kernel 0: lin0 pad only ----------------
__global__ void ccs_prep_kernel(const float* __restrict__ lin0_W,
                                float* __restrict__ ws) {
  int d = blockIdx.x * blockDim.x + threadIdx.x;
  if (d >= 9216) return;
  int ch = d % 36, hh = (d / 36) & 63, g = d / 2304;
  ws[d] = (ch < 33) ? lin0_W[(g * 64 + hh) * 33 + ch] : 0.f;
}

// ---------------- kernel 1: per-grid-point network ----------------
// v3: all weight streams are per-thread-contiguous float4 (4x fewer load
// insts, 4x bytes in flight) + one-ahead register prefetch in gp + LDS
// transposed activation copy so lin reads ds_read_b128.
__launch_bounds__(512)
__global__ void ccs_net_kernel(const float* __restrict__ condition,
                               const float* __restrict__ rel_pos_sigma,
                               const float* __restrict__ lin0_b,
                               const float* __restrict__ act0_a,
                               const float* __restrict__ act0_b,
                               const float* __restrict__ lins_b,
                               const float* __restrict__ acts_a,
                               const float* __restrict__ acts_b,
                               const float* __restrict__ out_b,
                               const float* __restrict__ shell_sigma,
                               const float* __restrict__ lins_W,
                               const float* __restrict__ gps_w,
                               const float* __restrict__ out_W,
                               const float* __restrict__ ws,
                               float* __restrict__ kws) {
  const float* lin0t = ws + OFF_LIN0T;

  __shared__ float xb[33 * 8];  // condition channels (shared by both pts)
  __shared__ float x0r[2][8];   // per-point geometric row (ch 0)
  __shared__ __align__(16) float F0[2 * 512];
  __shared__ __align__(16) float F1[2 * 512];
  __shared__ __align__(16) float FT[2 * 512];   // transposed [pt][b][i] for lin
  __shared__ float part[2 * 8 * 8 * 64];        // [pt][isub][j][o]

  const int tid = threadIdx.x;
  const int n0 = blockIdx.x * 2;
  const int n1 = n0 + 1;

  const float sig = rel_pos_sigma[0];

  float qq[2];
  {
    int iz = n0 % 7, iy = (n0 / 7) % 7, ix = n0 / 49;
    float px = (float)ix - 3.f, py = (float)iy - 3.f, pz = (float)iz - 3.f;
    qq[0] = px * px + py * py + pz * pz;
  }
  {
    int nc = (n1 < NGRID) ? n1 : (NGRID - 1);
    int iz = nc % 7, iy = (nc / 7) % 7, ix = nc / 49;
    float px = (float)ix - 3.f, py = (float)iy - 3.f, pz = (float)iz - 3.f;
    qq[1] = px * px + py * py + pz * pz;
  }

  for (int t = tid; t < 264; t += 512) {
    int ch = t >> 3, b = t & 7;
    xb[t] = (ch == 0) ? 0.f : condition[(ch - 1) * 8 + b];
  }
  if (tid < 16) {
    int pt = tid >> 3, b = tid & 7;
    int nc = n0 + pt;
    if (nc >= NGRID) nc = NGRID - 1;
    int iz = nc % 7, iy = (nc / 7) % 7, ix = nc / 49;
    float px = (float)ix - 3.f, py = (float)iy - 3.f, pz = (float)iz - 3.f;
    float q = px * px + py * py + pz * pz;
    float scal = expf(-q / (2.f * sig * sig));
    x0r[pt][b] =
        (b == 0) ? scal : (b == 1) ? px : (b == 2) ? py : (b == 3) ? pz : 0.f;
  }
  __syncthreads();

  const int b8 = tid & 7;
  const int hh = (tid >> 3) & 63;
  const int gb = TB.grade[b8];

  // ---- lin0: contiguous padded row, 9 x float4 per thread ----
  {
    const float4* w4 = (const float4*)(lin0t + (gb * 64 + hh) * 36);
    float wv[36];
    #pragma unroll
    for (int t2 = 0; t2 < 9; ++t2) ((float4*)wv)[t2] = w4[t2];
    float a0 = wv[0] * x0r[0][b8];
    float a1 = wv[0] * x0r[1][b8];
    if (b8 == 0) {
      float bb = lin0_b[hh];
      a0 += bb;
      a1 += bb;
    }
    #pragma unroll
    for (int ch = 1; ch < 33; ++ch) {
      float xv = xb[ch * 8 + b8];
      a0 = fmaf(wv[ch], xv, a0);
      a1 = fmaf(wv[ch], xv, a1);
    }
    F0[hh * 8 + b8] = a0;
    F0[512 + hh * 8 + b8] = a1;
  }
  __syncthreads();

  // ---- helpers ----
  auto silu = [&](const float* src, float* dst, const float* aa,
                  const float* bb) {
    int s0 = (gb == 0) ? 0 : (gb == 1) ? 1 : (gb == 2) ? 4 : 7;
    int cnt = (gb == 0 || gb == 3) ? 1 : 3;
    float A = aa[hh * 4 + gb], B = bb[hh * 4 + gb];
    #pragma unroll
    for (int pt = 0; pt < 2; ++pt) {
      float qg = 0.f;
      for (int u = 0; u < cnt; ++u) {
        float v = src[pt * 512 + hh * 8 + s0 + u];
        qg = fmaf(v, v, qg);
      }
      float z = fmaf(A, qg, B);
      float gate = 1.f / (1.f + expf(-z));
      dst[pt * 512 + hh * 8 + b8] = src[pt * 512 + hh * 8 + b8] * gate;
    }
  };

  // lin reads the transposed activation copy (FT) with ds_read_b128 and
  // weights directly from lins_W ([g][hh][i], i contiguous -> 16 float4).
  auto lin = [&](float* dst, const float* wt, const float* bias) {
    const float4* w4 = (const float4*)(wt + gb * 4096 + hh * 64);
    const float4* sA = (const float4*)(FT + b8 * 64);
    const float4* sB = (const float4*)(FT + 512 + b8 * 64);
    float a0 = 0.f, a1 = 0.f;
    if (b8 == 0) {
      float bb = bias[hh];
      a0 = bb;
      a1 = bb;
    }
    #pragma unroll
    for (int i4 = 0; i4 < 16; ++i4) {
      float wv[4], xa[4], xbv[4];
      *(float4*)wv = w4[i4];
      *(float4*)xa = sA[i4];
      *(float4*)xbv = sB[i4];
      #pragma unroll
      for (int u = 0; u < 4; ++u) {
        a0 = fmaf(wv[u], xa[u], a0);
        a1 = fmaf(wv[u], xbv[u], a1);
      }
    }
    dst[hh * 8 + b8] = a0;
    dst[512 + hh * 8 + b8] = a1;
  };

  // gp: weights straight from gps_w ([o][i][p], p contiguous -> 5 float4 per
  // (o,i), 640 contiguous bytes per thread per layer) + one-ahead prefetch.
  auto gp = [&](const float* src, float* dst, const float* wl) {
    const int o = tid & 63;
    const int isub = tid >> 6;  // 0..7, 8 i's each
    float fa[8], fb[8];
    #pragma unroll
    for (int j = 0; j < 8; ++j) {
      fa[j] = 0.f;
      fb[j] = 0.f;
    }
    const float4* wb4 =
        (const float4*)(wl + (size_t)o * 1280 + (size_t)isub * 160);
    float4 wq[5];
    #pragma unroll
    for (int t2 = 0; t2 < 5; ++t2) wq[t2] = wb4[t2];
    #pragma unroll
    for (int it = 0; it < 8; ++it) {
      float4 wn[5];
      if (it < 7) {
        const float4* nb = wb4 + (it + 1) * 5;
        #pragma unroll
        for (int t2 = 0; t2 < 5; ++t2) wn[t2] = nb[t2];
      }
      int i = isub * 8 + it;
      float4 va0 = *(const float4*)(src + i * 8);
      float4 va1 = *(const float4*)(src + i * 8 + 4);
      float4 vb0 = *(const float4*)(src + 512 + i * 8);
      float4 vb1 = *(const float4*)(src + 512 + i * 8 + 4);
      float xA[8] = {va0.x, va0.y, va0.z, va0.w, va1.x, va1.y, va1.z, va1.w};
      float xB[8] = {vb0.x, vb0.y, vb0.z, vb0.w, vb1.x, vb1.y, vb1.z, vb1.w};
      float wp[20];
      #pragma unroll
      for (int t2 = 0; t2 < 5; ++t2) ((float4*)wp)[t2] = wq[t2];
      #pragma unroll
      for (int k = 0; k < 8; ++k) {
        #pragma unroll
        for (int m = 0; m < 8; ++m) {
          const int j = TB.prod_idx[k][m];
          const int p = TB.pid[TB.grade[k]][TB.grade[j]][TB.grade[m]];
          if (TB.prod_sgn[k][m] > 0) {
            fa[j] = fmaf(xA[k] * xA[m], wp[p], fa[j]);
            fb[j] = fmaf(xB[k] * xB[m], wp[p], fb[j]);
          } else {
            fa[j] = fmaf(-xA[k] * xA[m], wp[p], fa[j]);
            fb[j] = fmaf(-xB[k] * xB[m], wp[p], fb[j]);
          }
        }
      }
      if (it < 7) {
        #pragma unroll
        for (int t2 = 0; t2 < 5; ++t2) wq[t2] = wn[t2];
      }
    }
    #pragma unroll
    for (int j = 0; j < 8; ++j) {
      part[isub * 512 + j * 64 + o] = fa[j];
      part[4096 + isub * 512 + j * 64 + o] = fb[j];
    }
    __syncthreads();
    #pragma unroll
    for (int r = 0; r < 2; ++r) {
      int item = tid + r * 512;  // 1024 items = 2pt x 8j x 64o
      int oo = item & 63;
      int j = (item >> 6) & 7;
      int pt = item >> 9;
      const float* pp = part + pt * 4096 + j * 64 + oo;
      float s = pp[0] + pp[512] + pp[1024] + pp[1536] + pp[2048] + pp[2560] +
                pp[3072] + pp[3584];
      s *= 0.125f;
      dst[pt * 512 + oo * 8 + j] = s;
      FT[pt * 512 + j * 64 + oo] = s;  // transposed copy for next lin
    }
    __syncthreads();
  };

  // ---- layer 0 ----
  silu(F0, F1, act0_a, act0_b);
  __syncthreads();
  gp(F1, F0, gps_w + 0);  // features now in F0 (+FT)

  // ---- layers 1..3 ----
  float* f = F0;
  float* g_ = F1;
  for (int l = 0; l < 3; ++l) {
    lin(g_, lins_W + l * 16384, lins_b + l * 64);
    __syncthreads();
    silu(g_, f, acts_a + l * 256, acts_b + l * 256);
    __syncthreads();
    gp(f, g_, gps_w + (size_t)(l + 1) * 81920);  // result in g_ (+FT)
    float* t = f; f = g_; g_ = t;                // features in f
  }

  // ---- output linear + shell: both oc's of this thread per fetch ----
  const float FACTOR = 1.0f / sqrtf(343.0f);
  {
    const int oc0 = tid;
    const int oc1 = tid + 512;
    float acc[2][2][8];  // [r][pt][b]
    #pragma unroll
    for (int r2 = 0; r2 < 2; ++r2)
      #pragma unroll
      for (int pt = 0; pt < 2; ++pt)
        #pragma unroll
        for (int b = 0; b < 8; ++b) acc[r2][pt][b] = 0.f;
    {
      float b0 = out_b[oc0], b1 = out_b[oc1];
      acc[0][0][0] = b0; acc[0][1][0] = b0;
      acc[1][0][0] = b1; acc[1][1][0] = b1;
    }
    const float4* ow4 = (const float4*)out_W;  // [g][oc][i]/4
    #pragma unroll 4
    for (int i4 = 0; i4 < 16; ++i4) {
      float w[2][4][4];  // [r][g][u]
      #pragma unroll
      for (int g = 0; g < 4; ++g) {
        *(float4*)w[0][g] = ow4[((size_t)g * 1024 + oc0) * 16 + i4];
        *(float4*)w[1][g] = ow4[((size_t)g * 1024 + oc1) * 16 + i4];
      }
      #pragma unroll
      for (int u = 0; u < 4; ++u) {
        int i = i4 * 4 + u;
        #pragma unroll
        for (int pt = 0; pt < 2; ++pt) {
          float h[8];
          *(float4*)h = *(const float4*)(f + pt * 512 + i * 8);
          *(float4*)(h + 4) = *(const float4*)(f + pt * 512 + i * 8 + 4);
          #pragma unroll
          for (int r2 = 0; r2 < 2; ++r2) {
            acc[r2][pt][0] = fmaf(w[r2][0][u], h[0], acc[r2][pt][0]);
            acc[r2][pt][1] = fmaf(w[r2][1][u], h[1], acc[r2][pt][1]);
            acc[r2][pt][2] = fmaf(w[r2][1][u], h[2], acc[r2][pt][2]);
            acc[r2][pt][3] = fmaf(w[r2][1][u], h[3], acc[r2][pt][3]);
            acc[r2][pt][4] = fmaf(w[r2][2][u], h[4], acc[r2][pt][4]);
            acc[r2][pt][5] = fmaf(w[r2][2][u], h[5], acc[r2][pt][5]);
            acc[r2][pt][6] = fmaf(w[r2][2][u], h[6], acc[r2][pt][6]);
            acc[r2][pt][7] = fmaf(w[r2][3][u], h[7], acc[r2][pt][7]);
          }
        }
      }
    }
    #pragma unroll
    for (int r2 = 0; r2 < 2; ++r2) {
      int oc = tid + r2 * 512;
      float sh[8];
      *(float4*)sh = *(const float4*)(shell_sigma + oc * 8);
      *(float4*)(sh + 4) = *(const float4*)(shell_sigma + oc * 8 + 4);
      #pragma unroll
      for (int pt = 0; pt < 2; ++pt) {
        int n = n0 + pt;
        if (n < NGRID) {
          float q = qq[pt];
          float out8[8];
          #pragma unroll
          for (int b = 0; b < 8; ++b)
            out8[b] = acc[r2][pt][b] * expf(-q / (sh[b] * sh[b])) * FACTOR;
          float4* dstp = (float4*)(kws + ((size_t)oc * 343 + n) * 8);
          dstp[0] = make_float4(out8[0], out8[1], out8[2], out8[3]);
          dstp[1] = make_float4(out8[4], out8[5], out8[6], out8[7]);
        }
      }
    }
  }
}

// ---------------- kernel 2: Cayley expansion to output ----------------
__launch_bounds__(64)
__global__ void ccs_expand_kernel(const float* __restrict__ cayley_w,
                                  const float* __restrict__ kws,
                                  float* __restrict__ out) {
  const int oi = blockIdx.x;  // o*32 + i
  const int o = oi >> 5, i = oi & 31;
  const int n = blockIdx.y * 64 + threadIdx.x;
  if (n >= NGRID) return;
  float cw[20];
  {
    const float4* c4 = (const float4*)(cayley_w + oi * 20);
    #pragma unroll
    for (int t2 = 0; t2 < 5; ++t2) ((float4*)cw)[t2] = c4[t2];
  }
  float k8[8];
  {
    const float4* kp4 = (const float4*)(kws + ((size_t)oi * 343 + n) * 8);
    *(float4*)k8 = kp4[0];
    *(float4*)(k8 + 4) = kp4[1];
  }
  #pragma unroll
  for (int l = 0; l < 8; ++l) {
    #pragma unroll
    for (int m = 0; m < 8; ++m) {
      const int kk = TB.kk_idx[l][m];
      const int p = TB.pid[TB.grade[kk]][TB.grade[l]][TB.grade[m]];
      float v = k8[kk] * cw[p];
      if (TB.kk_sgn[l][m] < 0) v = -v;
      out[((size_t)((o * 8 + l) * 256 + i * 8 + m)) * 343 + n] = v;
    }
  }
}

extern "C" void kernel_launch(void* const* d_in, const int* in_sizes, int n_in,
                              void* d_out, int out_size, void* d_ws,
                              size_t ws_size, hipStream_t stream) {
  const float* condition     = (const float*)d_in[0];
  const float* rel_pos_sigma = (const float*)d_in[1];
  const float* cayley_w      = (const float*)d_in[2];
  const float* lin0_W        = (const float*)d_in[3];
  const float* lin0_b        = (const float*)d_in[4];
  const float* act0_a        = (const float*)d_in[5];
  const float* act0_b        = (const float*)d_in[6];
  const float* gps_w         = (const float*)d_in[7];
  const float* lins_W        = (const float*)d_in[8];
  const float* lins_b        = (const float*)d_in[9];
  const float* acts_a        = (const float*)d_in[10];
  const float* acts_b        = (const float*)d_in[11];
  const float* out_W         = (const float*)d_in[12];
  const float* out_b         = (const float*)d_in[13];
  const float* shell_sigma   = (const float*)d_in[14];

  float* ws = (float*)d_ws;
  float* kws = ws + OFF_KWS;
  float* out = (float*)d_out;

  ccs_prep_kernel<<<dim3(36), dim3(256), 0, stream>>>(lin0_W, ws);
  ccs_net_kernel<<<dim3((NGRID + 1) / 2), dim3(512), 0, stream>>>(
      condition, rel_pos_sigma, lin0_b, act0_a, act0_b, lins_b, acts_a, acts_b,
      out_b, shell_sigma, lins_W, gps_w, out_W, ws, kws);
  ccs_expand_kernel<<<dim3(1024, 6), dim3(64), 0, stream>>>(cayley_w, kws, out);
}